// Round 9
// baseline (612.331 us; speedup 1.0000x reference)
//
#include <hip/hip_runtime.h>
#include <cstdint>
#include <cmath>

#define HID 32
#define GATES 96  // 3*HID
#define F 128
#define CAP 68    // fixed per-node segment capacity; P(deg>68) ~ 1e-9/node (Poisson mean 32)

typedef float nfloat2 __attribute__((ext_vector_type(2)));

__device__ inline unsigned f2b(float x) {   // f32 -> bf16 (RNE)
    unsigned u = __float_as_uint(x);
    return (u + 0x7FFFu + ((u >> 16) & 1u)) >> 16;
}

// ws layout (float units): xwh[N*48] (N*96 bf16) | sorted[N*CAP*2] | dinv[N] | cnt[N]

__global__ __launch_bounds__(256) void k_zero(unsigned* __restrict__ cnt, int N) {
    int i = blockIdx.x * 256 + threadIdx.x;
    if (i < N) cnt[i] = 0u;
}

// fused histogram + direct placement into fixed-capacity segments (the only atomics)
__global__ __launch_bounds__(256) void k_build(const int* __restrict__ ei,
        const float* __restrict__ w, unsigned* __restrict__ cnt,
        float2* __restrict__ sorted, int E) {
    int e = blockIdx.x * 256 + threadIdx.x;
    if (e >= E) return;
    int s = ei[e];
    int d = ei[(size_t)E + e];
    unsigned r = atomicAdd(&cnt[d], 1u);
    if (r < CAP) sorted[(size_t)d * CAP + r] = make_float2(__int_as_float(s), w[e]);
}

// dinv[n] = rsqrt(1 + sum w over segment)
__global__ __launch_bounds__(256) void k_degsum(const unsigned* __restrict__ cnt,
        const float2* __restrict__ sorted, float* __restrict__ dinv, int N) {
    int l = threadIdx.x & 31;
    int n = blockIdx.x * 8 + (threadIdx.x >> 5);
    if (n >= N) return;
    unsigned len = cnt[n]; if (len > CAP) len = CAP;
    size_t base = (size_t)n * CAP;
    float s = 0.0f;
    for (unsigned i = l; i < len; i += 32) s += sorted[base + i].y;
    #pragma unroll
    for (int o = 16; o >= 1; o >>= 1) s += __shfl_xor(s, o, 32);
    if (l == 0) dinv[n] = rsqrtf(1.0f + s);
}

// xwh[n][c] (bf16) = x[n][:] @ [Wz|Wr|Wh][:, c]
#define GR 16
__global__ __launch_bounds__(256) void k_gemm(const float* __restrict__ x,
        const float* __restrict__ Wz, const float* __restrict__ Wr, const float* __restrict__ Wh,
        unsigned* __restrict__ xwh, int N) {
    __shared__ float Wl[F * GATES];
    __shared__ float xs[GR][F + 1];
    int tid = threadIdx.x;
    for (int i = tid; i < F * GATES; i += 256) {
        int k = i / GATES, c = i % GATES;
        float v;
        if (c < 32)      v = Wz[k * 32 + c];
        else if (c < 64) v = Wr[k * 32 + (c - 32)];
        else             v = Wh[k * 32 + (c - 64)];
        Wl[i] = v;
    }
    int r_local = tid / 16;
    int cb = tid % 16;
    int ntiles = (N + GR - 1) / GR;
    for (int t = blockIdx.x; t < ntiles; t += gridDim.x) {
        int row0 = t * GR;
        __syncthreads();
        for (int i = tid; i < GR * F; i += 256) {
            int r = i / F, k = i % F;
            int g = row0 + r;
            xs[r][k] = (g < N) ? x[(size_t)g * F + k] : 0.0f;
        }
        __syncthreads();
        int grow = row0 + r_local;
        if (grow < N) {
            float acc[6] = {0, 0, 0, 0, 0, 0};
            for (int k = 0; k < F; ++k) {
                float xv = xs[r_local][k];
                const float* wr = &Wl[k * GATES + cb * 6];
                #pragma unroll
                for (int j = 0; j < 6; ++j) acc[j] += xv * wr[j];
            }
            unsigned* o = xwh + (size_t)grow * 48 + cb * 3;
            o[0] = f2b(acc[0]) | (f2b(acc[1]) << 16);
            o[1] = f2b(acc[2]) | (f2b(acc[3]) << 16);
            o[2] = f2b(acc[4]) | (f2b(acc[5]) << 16);
        }
    }
}

// one 32-lane group per dst node, two 16-lane halves (one edge each per unrolled step).
// chunk padded to 32 edges (compile-time 16-step unroll) so ~16 gathers stay in flight.
__global__ __launch_bounds__(256, 4) void k_fused(
        const unsigned* __restrict__ cnt, const float2* __restrict__ sorted,
        const unsigned* __restrict__ xwh, const float* __restrict__ dinv, const float* __restrict__ Hin,
        const float* __restrict__ bz, const float* __restrict__ br, const float* __restrict__ bh,
        const float* __restrict__ Lzw, const float* __restrict__ Lzb,
        const float* __restrict__ Lrw, const float* __restrict__ Lrb,
        const float* __restrict__ Lhw, const float* __restrict__ Lhb,
        const float* __restrict__ linw, const float* __restrict__ linb,
        float* __restrict__ out_probs, float* __restrict__ out_H, int N) {
    int tid = threadIdx.x;
    int l = tid & 31;
    int half = l >> 4;
    int m = l & 15;
    int n = blockIdx.x * 8 + (tid >> 5);
    if (n >= N) return;

    float di = dinv[n];
    float acc0 = 0, acc1 = 0, acc2 = 0, acc3 = 0, acc4 = 0, acc5 = 0;

    unsigned len = cnt[n]; if (len > CAP) len = CAP;
    size_t base = (size_t)n * CAP;
    for (unsigned i0 = 0; i0 < len; i0 += 32) {
        int take = (int)(len - i0); if (take > 32) take = 32;
        nfloat2 ev = {0.0f, 0.0f};
        if (l < take)
            ev = __builtin_nontemporal_load((const nfloat2*)sorted + base + i0 + l);
        int   se = __float_as_int(ev.x);     // 0 for padded lanes
        float me = ev.y * dinv[se];          // 0 for padded lanes
        #pragma unroll
        for (int j = 0; j < 32; j += 2) {
            int jj = j + half;
            int   sj = __shfl(se, jj, 32);
            float mj = __shfl(me, jj, 32);
            const unsigned* p = xwh + (size_t)sj * 48 + m * 3;
            unsigned u0 = p[0], u1 = p[1], u2 = p[2];
            acc0 += mj * __uint_as_float(u0 << 16);
            acc1 += mj * __uint_as_float(u0 & 0xFFFF0000u);
            acc2 += mj * __uint_as_float(u1 << 16);
            acc3 += mj * __uint_as_float(u1 & 0xFFFF0000u);
            acc4 += mj * __uint_as_float(u2 << 16);
            acc5 += mj * __uint_as_float(u2 & 0xFFFF0000u);
        }
    }
    // fold the two halves
    acc0 += __shfl_xor(acc0, 16, 32);
    acc1 += __shfl_xor(acc1, 16, 32);
    acc2 += __shfl_xor(acc2, 16, 32);
    acc3 += __shfl_xor(acc3, 16, 32);
    acc4 += __shfl_xor(acc4, 16, 32);
    acc5 += __shfl_xor(acc5, 16, 32);
    // self-loop + di scale + bias: g_i = di*(acc_i + di*x_i) + b[f], f = m*6+i
    float g0, g1, g2, g3, g4, g5;
    {
        const unsigned* p = xwh + (size_t)n * 48 + m * 3;
        unsigned u0 = p[0], u1 = p[1], u2 = p[2];
        #define BIAS(f) ((f) < 32 ? bz[(f)] : ((f) < 64 ? br[(f) - 32] : bh[(f) - 64]))
        int f = m * 6;
        g0 = di * (acc0 + di * __uint_as_float(u0 << 16))         + BIAS(f);
        g1 = di * (acc1 + di * __uint_as_float(u0 & 0xFFFF0000u)) + BIAS(f + 1);
        g2 = di * (acc2 + di * __uint_as_float(u1 << 16))         + BIAS(f + 2);
        g3 = di * (acc3 + di * __uint_as_float(u1 & 0xFFFF0000u)) + BIAS(f + 3);
        g4 = di * (acc4 + di * __uint_as_float(u2 << 16))         + BIAS(f + 4);
        g5 = di * (acc5 + di * __uint_as_float(u2 & 0xFFFF0000u)) + BIAS(f + 5);
        #undef BIAS
    }
    // transpose to per-lane-feature layout: lane l wants feature f at (mm=f/6, ii=f%6)
    #define GATHERF(out, fexp) { int ff = (fexp); int mm = ff / 6, ii = ff % 6;            \
        float t0 = __shfl(g0, mm, 32), t1 = __shfl(g1, mm, 32), t2 = __shfl(g2, mm, 32),   \
              t3 = __shfl(g3, mm, 32), t4 = __shfl(g4, mm, 32), t5 = __shfl(g5, mm, 32);   \
        out = ii == 0 ? t0 : ii == 1 ? t1 : ii == 2 ? t2 : ii == 3 ? t3 : ii == 4 ? t4 : t5; }
    float gz, gr, gh;
    GATHERF(gz, l);
    GATHERF(gr, 32 + l);
    GATHERF(gh, 64 + l);
    #undef GATHERF

    float Hd = Hin[(size_t)n * HID + l];

    float az = Lzb[l], ar = Lrb[l];
    #pragma unroll 4
    for (int k = 0; k < 32; ++k) {
        float gzk = __shfl(gz, k, 32);
        float grk = __shfl(gr, k, 32);
        float Hk  = __shfl(Hd, k, 32);
        az += gzk * Lzw[k * 32 + l] + Hk * Lzw[(32 + k) * 32 + l];
        ar += grk * Lrw[k * 32 + l] + Hk * Lrw[(32 + k) * 32 + l];
    }
    float Z  = 1.0f / (1.0f + __expf(-az));
    float Rg = 1.0f / (1.0f + __expf(-ar));
    float HR = Hd * Rg;
    float ah = Lhb[l];
    #pragma unroll 4
    for (int k = 0; k < 32; ++k) {
        float ghk = __shfl(gh, k, 32);
        float HRk = __shfl(HR, k, 32);
        ah += ghk * Lhw[k * 32 + l] + HRk * Lhw[(32 + k) * 32 + l];
    }
    float Ht = tanhf(ah);
    float Hn = Z * Hd + (1.0f - Z) * Ht;
    float h = fmaxf(Hn, 0.0f);

    float logit = (l < 10) ? linb[l] : -INFINITY;
    #pragma unroll 4
    for (int k = 0; k < 32; ++k) {
        float hk = __shfl(h, k, 32);
        if (l < 10) logit += hk * linw[k * 10 + l];
    }
    float mx = logit;
    #pragma unroll
    for (int o = 8; o >= 1; o >>= 1) mx = fmaxf(mx, __shfl_xor(mx, o, 16));
    float ex = (l < 10) ? __expf(logit - mx) : 0.0f;
    float sum = ex;
    #pragma unroll
    for (int o = 8; o >= 1; o >>= 1) sum += __shfl_xor(sum, o, 16);
    if (l < 10) out_probs[(size_t)n * 10 + l] = ex / sum;
    out_H[(size_t)n * HID + l] = Hd;
}

extern "C" void kernel_launch(void* const* d_in, const int* in_sizes, int n_in,
                              void* d_out, int out_size, void* d_ws, size_t ws_size,
                              hipStream_t stream) {
    const float* x    = (const float*)d_in[0];
    const int*   ei   = (const int*)d_in[1];     // int32, layout [2][E]
    const float* ew   = (const float*)d_in[2];
    const float* H    = (const float*)d_in[3];
    const float* Wz   = (const float*)d_in[4];
    const float* bz   = (const float*)d_in[5];
    const float* Wr   = (const float*)d_in[6];
    const float* br   = (const float*)d_in[7];
    const float* Wh   = (const float*)d_in[8];
    const float* bh   = (const float*)d_in[9];
    const float* Lzw  = (const float*)d_in[10];
    const float* Lzb  = (const float*)d_in[11];
    const float* Lrw  = (const float*)d_in[12];
    const float* Lrb  = (const float*)d_in[13];
    const float* Lhw  = (const float*)d_in[14];
    const float* Lhb  = (const float*)d_in[15];
    const float* linw = (const float*)d_in[16];
    const float* linb = (const float*)d_in[17];

    int N = in_sizes[0] / F;
    int E = in_sizes[2];

    float* ws = (float*)d_ws;
    unsigned* xwh    = (unsigned*)ws;                             // N*48 u32 (N*96 bf16)
    float2*   sorted = (float2*)(ws + (size_t)N * 48);            // N*CAP float2
    float*    dinv   = ws + (size_t)N * 48 + (size_t)N * CAP * 2;
    unsigned* cnt    = (unsigned*)(dinv + N);

    float* out_probs = (float*)d_out;
    float* out_H     = (float*)d_out + (size_t)N * 10;

    k_zero<<<(N + 255) / 256, 256, 0, stream>>>(cnt, N);
    k_build<<<(E + 255) / 256, 256, 0, stream>>>(ei, ew, cnt, sorted, E);
    k_degsum<<<(N + 7) / 8, 256, 0, stream>>>(cnt, sorted, dinv, N);
    k_gemm<<<2048, 256, 0, stream>>>(x, Wz, Wr, Wh, xwh, N);
    k_fused<<<(N + 7) / 8, 256, 0, stream>>>(cnt, sorted, xwh, dinv, H,
                                             bz, br, bh, Lzw, Lzb, Lrw, Lrb, Lhw, Lhb,
                                             linw, linb, out_probs, out_H, N);
}

// Round 10
// 549.113 us; speedup vs baseline: 1.1151x; 1.1151x over previous
//
#include <hip/hip_runtime.h>
#include <cstdint>
#include <cmath>

#define HID 32
#define GATES 96  // 3*HID
#define F 128
#define CHUNK 256

typedef float nfloat2 __attribute__((ext_vector_type(2)));

__device__ inline unsigned f2b(float x) {   // f32 -> bf16 (RNE)
    unsigned u = __float_as_uint(x);
    return (u + 0x7FFFu + ((u >> 16) & 1u)) >> 16;
}

// ws layout (float units): xwh[N*48] (N*96 bf16) | sorted[E*2] | dinv[N] | cnt[N] | off[N] | csum[nchunk]
// rank[E] (u32) OVERLAYS xwh: rank dies at k_permute, before k_gemm writes xwh.

__global__ __launch_bounds__(256) void k_setup(unsigned* __restrict__ cnt, int N) {
    int i = blockIdx.x * 256 + threadIdx.x;
    if (i < N) cnt[i] = 0u;
}

// the only atomics in the pipeline: rank[e] = old count (edge's slot in its dst segment)
__global__ __launch_bounds__(256) void k_hist(const int* __restrict__ ei_dst,
                                              unsigned* __restrict__ cnt,
                                              unsigned* __restrict__ rank, int E) {
    int e = blockIdx.x * 256 + threadIdx.x;
    if (e >= E) return;
    rank[e] = atomicAdd(&cnt[ei_dst[e]], 1u);
}

__global__ __launch_bounds__(256) void k_chunksum(const unsigned* __restrict__ cnt,
                                                  unsigned* __restrict__ csum, int N) {
    __shared__ unsigned s[256];
    int i = blockIdx.x * 256 + threadIdx.x;
    s[threadIdx.x] = (i < N) ? cnt[i] : 0u;
    __syncthreads();
    for (int off = 128; off > 0; off >>= 1) {
        if (threadIdx.x < off) s[threadIdx.x] += s[threadIdx.x + off];
        __syncthreads();
    }
    if (threadIdx.x == 0) csum[blockIdx.x] = s[0];
}

__global__ __launch_bounds__(1024) void k_scanchunks(unsigned* __restrict__ csum, int nc) {
    __shared__ unsigned s[1024];
    int t = threadIdx.x;
    unsigned v = (t < nc) ? csum[t] : 0u;
    s[t] = v;
    __syncthreads();
    for (int o = 1; o < 1024; o <<= 1) {
        unsigned x = s[t];
        if (t >= o) x += s[t - o];
        __syncthreads();
        s[t] = x;
        __syncthreads();
    }
    if (t < nc) csum[t] = s[t] - v;   // exclusive
}

__global__ __launch_bounds__(256) void k_scanapply(const unsigned* __restrict__ cnt,
                                                   const unsigned* __restrict__ csum,
                                                   unsigned* __restrict__ off, int N) {
    __shared__ unsigned s[2][256];
    int t = threadIdx.x, i = blockIdx.x * 256 + t;
    unsigned v = (i < N) ? cnt[i] : 0u;
    int cur = 0;
    s[0][t] = v;
    __syncthreads();
    for (int o = 1; o < 256; o <<= 1) {
        unsigned x = s[cur][t];
        if (t >= o) x += s[cur][t - o];
        s[cur ^ 1][t] = x;
        cur ^= 1;
        __syncthreads();
    }
    unsigned excl = s[cur][t] - v + csum[blockIdx.x];
    if (i < N) off[i] = excl;
}

// atomic-free permute: slot = off[d] + rank[e]; payload (src, raw w)
__global__ __launch_bounds__(256) void k_permute(const int* __restrict__ ei,
        const float* __restrict__ w, const unsigned* __restrict__ off,
        const unsigned* __restrict__ rank, float2* __restrict__ sorted, int E) {
    int e = blockIdx.x * 256 + threadIdx.x;
    if (e >= E) return;
    int s = ei[e];
    int d = ei[(size_t)E + e];
    unsigned p = off[d] + rank[e];
    sorted[p] = make_float2(__int_as_float(s), w[e]);
}

// dinv[n] = rsqrt(1 + sum w over CSR segment)
__global__ __launch_bounds__(256) void k_degsum(const unsigned* __restrict__ off,
        const unsigned* __restrict__ cnt, const float2* __restrict__ sorted,
        float* __restrict__ dinv, int N) {
    int l = threadIdx.x & 31;
    int n = blockIdx.x * 8 + (threadIdx.x >> 5);
    if (n >= N) return;
    unsigned base = off[n], len = cnt[n];
    float s = 0.0f;
    for (unsigned i = l; i < len; i += 32) s += sorted[base + i].y;
    #pragma unroll
    for (int o = 16; o >= 1; o >>= 1) s += __shfl_xor(s, o, 32);
    if (l == 0) dinv[n] = rsqrtf(1.0f + s);
}

// xwh[n][c] (bf16) = x[n][:] @ [Wz|Wr|Wh][:, c]
#define GR 16
__global__ __launch_bounds__(256) void k_gemm(const float* __restrict__ x,
        const float* __restrict__ Wz, const float* __restrict__ Wr, const float* __restrict__ Wh,
        unsigned* __restrict__ xwh, int N) {
    __shared__ float Wl[F * GATES];
    __shared__ float xs[GR][F + 1];
    int tid = threadIdx.x;
    for (int i = tid; i < F * GATES; i += 256) {
        int k = i / GATES, c = i % GATES;
        float v;
        if (c < 32)      v = Wz[k * 32 + c];
        else if (c < 64) v = Wr[k * 32 + (c - 32)];
        else             v = Wh[k * 32 + (c - 64)];
        Wl[i] = v;
    }
    int r_local = tid / 16;
    int cb = tid % 16;
    int ntiles = (N + GR - 1) / GR;
    for (int t = blockIdx.x; t < ntiles; t += gridDim.x) {
        int row0 = t * GR;
        __syncthreads();
        for (int i = tid; i < GR * F; i += 256) {
            int r = i / F, k = i % F;
            int g = row0 + r;
            xs[r][k] = (g < N) ? x[(size_t)g * F + k] : 0.0f;
        }
        __syncthreads();
        int grow = row0 + r_local;
        if (grow < N) {
            float acc[6] = {0, 0, 0, 0, 0, 0};
            for (int k = 0; k < F; ++k) {
                float xv = xs[r_local][k];
                const float* wr = &Wl[k * GATES + cb * 6];
                #pragma unroll
                for (int j = 0; j < 6; ++j) acc[j] += xv * wr[j];
            }
            unsigned* o = xwh + (size_t)grow * 48 + cb * 3;
            o[0] = f2b(acc[0]) | (f2b(acc[1]) << 16);
            o[1] = f2b(acc[2]) | (f2b(acc[3]) << 16);
            o[2] = f2b(acc[4]) | (f2b(acc[5]) << 16);
        }
    }
}

// one 32-lane group per dst node, two 16-lane halves (one edge each per step).
// Edge loop: guarded unrolled blocks of 8 edges (4 STEPs of 2) -> ~8+ gathers in flight,
// <=12% padded waste, all under the (256,8) 64-VGPR cap (R8 TLP + R9 ILP).
__global__ __launch_bounds__(256, 8) void k_fused(
        const unsigned* __restrict__ off, const unsigned* __restrict__ cnt,
        const float2* __restrict__ sorted,
        const unsigned* __restrict__ xwh, const float* __restrict__ dinv, const float* __restrict__ Hin,
        const float* __restrict__ bz, const float* __restrict__ br, const float* __restrict__ bh,
        const float* __restrict__ Lzw, const float* __restrict__ Lzb,
        const float* __restrict__ Lrw, const float* __restrict__ Lrb,
        const float* __restrict__ Lhw, const float* __restrict__ Lhb,
        const float* __restrict__ linw, const float* __restrict__ linb,
        float* __restrict__ out_probs, float* __restrict__ out_H, int N) {
    int tid = threadIdx.x;
    int l = tid & 31;
    int half = l >> 4;
    int m = l & 15;
    int n = blockIdx.x * 8 + (tid >> 5);
    if (n >= N) return;

    float di = dinv[n];
    float acc0 = 0, acc1 = 0, acc2 = 0, acc3 = 0, acc4 = 0, acc5 = 0;

    unsigned base = off[n], len = cnt[n];
    for (unsigned i0 = 0; i0 < len; i0 += 32) {
        int take = (int)(len - i0); if (take > 32) take = 32;
        nfloat2 ev = {0.0f, 0.0f};
        if (l < take)
            ev = __builtin_nontemporal_load((const nfloat2*)sorted + base + i0 + l);
        int   se = __float_as_int(ev.x);     // 0 for padded lanes
        float me = ev.y * dinv[se];          // 0 for padded lanes

        #define STEP(j) { int jj = (j) + half;                                   \
            int   sj = __shfl(se, jj, 32);                                       \
            float mj = __shfl(me, jj, 32);                                       \
            const unsigned* p = xwh + (size_t)sj * 48 + m * 3;                   \
            unsigned u0 = p[0], u1 = p[1], u2 = p[2];                            \
            acc0 += mj * __uint_as_float(u0 << 16);                              \
            acc1 += mj * __uint_as_float(u0 & 0xFFFF0000u);                      \
            acc2 += mj * __uint_as_float(u1 << 16);                              \
            acc3 += mj * __uint_as_float(u1 & 0xFFFF0000u);                      \
            acc4 += mj * __uint_as_float(u2 << 16);                              \
            acc5 += mj * __uint_as_float(u2 & 0xFFFF0000u); }

        STEP(0) STEP(2) STEP(4) STEP(6)
        if (take > 8)  { STEP(8)  STEP(10) STEP(12) STEP(14) }
        if (take > 16) { STEP(16) STEP(18) STEP(20) STEP(22) }
        if (take > 24) { STEP(24) STEP(26) STEP(28) STEP(30) }
        #undef STEP
    }
    // fold the two halves
    acc0 += __shfl_xor(acc0, 16, 32);
    acc1 += __shfl_xor(acc1, 16, 32);
    acc2 += __shfl_xor(acc2, 16, 32);
    acc3 += __shfl_xor(acc3, 16, 32);
    acc4 += __shfl_xor(acc4, 16, 32);
    acc5 += __shfl_xor(acc5, 16, 32);
    // self-loop + di scale + bias: g_i = di*(acc_i + di*x_i) + b[f], f = m*6+i
    float g0, g1, g2, g3, g4, g5;
    {
        const unsigned* p = xwh + (size_t)n * 48 + m * 3;
        unsigned u0 = p[0], u1 = p[1], u2 = p[2];
        #define BIAS(f) ((f) < 32 ? bz[(f)] : ((f) < 64 ? br[(f) - 32] : bh[(f) - 64]))
        int f = m * 6;
        g0 = di * (acc0 + di * __uint_as_float(u0 << 16))         + BIAS(f);
        g1 = di * (acc1 + di * __uint_as_float(u0 & 0xFFFF0000u)) + BIAS(f + 1);
        g2 = di * (acc2 + di * __uint_as_float(u1 << 16))         + BIAS(f + 2);
        g3 = di * (acc3 + di * __uint_as_float(u1 & 0xFFFF0000u)) + BIAS(f + 3);
        g4 = di * (acc4 + di * __uint_as_float(u2 << 16))         + BIAS(f + 4);
        g5 = di * (acc5 + di * __uint_as_float(u2 & 0xFFFF0000u)) + BIAS(f + 5);
        #undef BIAS
    }
    // transpose to per-lane-feature layout: lane l wants feature f at (mm=f/6, ii=f%6)
    #define GATHERF(out, fexp) { int ff = (fexp); int mm = ff / 6, ii = ff % 6;            \
        float t0 = __shfl(g0, mm, 32), t1 = __shfl(g1, mm, 32), t2 = __shfl(g2, mm, 32),   \
              t3 = __shfl(g3, mm, 32), t4 = __shfl(g4, mm, 32), t5 = __shfl(g5, mm, 32);   \
        out = ii == 0 ? t0 : ii == 1 ? t1 : ii == 2 ? t2 : ii == 3 ? t3 : ii == 4 ? t4 : t5; }
    float gz, gr, gh;
    GATHERF(gz, l);
    GATHERF(gr, 32 + l);
    GATHERF(gh, 64 + l);
    #undef GATHERF

    float Hd = Hin[(size_t)n * HID + l];

    float az = Lzb[l], ar = Lrb[l];
    #pragma unroll 4
    for (int k = 0; k < 32; ++k) {
        float gzk = __shfl(gz, k, 32);
        float grk = __shfl(gr, k, 32);
        float Hk  = __shfl(Hd, k, 32);
        az += gzk * Lzw[k * 32 + l] + Hk * Lzw[(32 + k) * 32 + l];
        ar += grk * Lrw[k * 32 + l] + Hk * Lrw[(32 + k) * 32 + l];
    }
    float Z  = 1.0f / (1.0f + __expf(-az));
    float Rg = 1.0f / (1.0f + __expf(-ar));
    float HR = Hd * Rg;
    float ah = Lhb[l];
    #pragma unroll 4
    for (int k = 0; k < 32; ++k) {
        float ghk = __shfl(gh, k, 32);
        float HRk = __shfl(HR, k, 32);
        ah += ghk * Lhw[k * 32 + l] + HRk * Lhw[(32 + k) * 32 + l];
    }
    float Ht = tanhf(ah);
    float Hn = Z * Hd + (1.0f - Z) * Ht;
    float h = fmaxf(Hn, 0.0f);

    float logit = (l < 10) ? linb[l] : -INFINITY;
    #pragma unroll 4
    for (int k = 0; k < 32; ++k) {
        float hk = __shfl(h, k, 32);
        if (l < 10) logit += hk * linw[k * 10 + l];
    }
    float mx = logit;
    #pragma unroll
    for (int o = 8; o >= 1; o >>= 1) mx = fmaxf(mx, __shfl_xor(mx, o, 16));
    float ex = (l < 10) ? __expf(logit - mx) : 0.0f;
    float sum = ex;
    #pragma unroll
    for (int o = 8; o >= 1; o >>= 1) sum += __shfl_xor(sum, o, 16);
    if (l < 10) out_probs[(size_t)n * 10 + l] = ex / sum;
    out_H[(size_t)n * HID + l] = Hd;
}

extern "C" void kernel_launch(void* const* d_in, const int* in_sizes, int n_in,
                              void* d_out, int out_size, void* d_ws, size_t ws_size,
                              hipStream_t stream) {
    const float* x    = (const float*)d_in[0];
    const int*   ei   = (const int*)d_in[1];     // int32, layout [2][E]
    const float* ew   = (const float*)d_in[2];
    const float* H    = (const float*)d_in[3];
    const float* Wz   = (const float*)d_in[4];
    const float* bz   = (const float*)d_in[5];
    const float* Wr   = (const float*)d_in[6];
    const float* br   = (const float*)d_in[7];
    const float* Wh   = (const float*)d_in[8];
    const float* bh   = (const float*)d_in[9];
    const float* Lzw  = (const float*)d_in[10];
    const float* Lzb  = (const float*)d_in[11];
    const float* Lrw  = (const float*)d_in[12];
    const float* Lrb  = (const float*)d_in[13];
    const float* Lhw  = (const float*)d_in[14];
    const float* Lhb  = (const float*)d_in[15];
    const float* linw = (const float*)d_in[16];
    const float* linb = (const float*)d_in[17];

    int N = in_sizes[0] / F;
    int E = in_sizes[2];
    int nchunk = (N + CHUNK - 1) / CHUNK;   // 391 for N=100k (scan supports <=1024)

    float* ws = (float*)d_ws;
    unsigned* xwh    = (unsigned*)ws;                       // N*48 u32 (N*96 bf16)
    float2*   sorted = (float2*)(ws + (size_t)N * 48);
    float*    dinv   = ws + (size_t)N * 48 + (size_t)E * 2;
    unsigned* cnt    = (unsigned*)(dinv + N);
    unsigned* off    = cnt + N;
    unsigned* csum   = off + N;
    unsigned* rank   = xwh;    // overlay: E u32 (12.8MB) <= N*48 u32 (19.2MB); dead before k_gemm

    float* out_probs = (float*)d_out;
    float* out_H     = (float*)d_out + (size_t)N * 10;

    k_setup<<<(N + 255) / 256, 256, 0, stream>>>(cnt, N);
    k_hist<<<(E + 255) / 256, 256, 0, stream>>>(ei + (size_t)E, cnt, rank, E);
    k_chunksum<<<nchunk, 256, 0, stream>>>(cnt, csum, N);
    k_scanchunks<<<1, 1024, 0, stream>>>(csum, nchunk);
    k_scanapply<<<nchunk, 256, 0, stream>>>(cnt, csum, off, N);
    k_permute<<<(E + 255) / 256, 256, 0, stream>>>(ei, ew, off, rank, sorted, E);
    k_degsum<<<(N + 7) / 8, 256, 0, stream>>>(off, cnt, sorted, dinv, N);
    k_gemm<<<2048, 256, 0, stream>>>(x, Wz, Wr, Wh, xwh, N);
    k_fused<<<(N + 7) / 8, 256, 0, stream>>>(off, cnt, sorted, xwh, dinv, H,
                                             bz, br, bh, Lzw, Lzb, Lrw, Lrb, Lhw, Lhb,
                                             linw, linb, out_probs, out_H, N);
}

// Round 11
// 531.722 us; speedup vs baseline: 1.1516x; 1.0327x over previous
//
#include <hip/hip_runtime.h>
#include <cstdint>
#include <cmath>

#define HID 32
#define GATES 96  // 3*HID
#define F 128
#define CHUNK 256

typedef float nfloat2 __attribute__((ext_vector_type(2)));

__device__ inline unsigned f2b(float x) {   // f32 -> bf16 (RNE)
    unsigned u = __float_as_uint(x);
    return (u + 0x7FFFu + ((u >> 16) & 1u)) >> 16;
}

// ws layout (float units): xwh[N*48] (N*96 bf16) | sorted[E*2] | dinv[N] | cnt[N] | off[N] | csum[nchunk]
// rank[E] (u32) OVERLAYS xwh: rank dies at k_permute, before k_gemm writes xwh.

// the only atomics in the pipeline: rank[e] = old count (edge's slot in its dst segment)
__global__ __launch_bounds__(256) void k_hist(const int* __restrict__ ei_dst,
                                              unsigned* __restrict__ cnt,
                                              unsigned* __restrict__ rank, int E) {
    int e = blockIdx.x * 256 + threadIdx.x;
    if (e >= E) return;
    rank[e] = atomicAdd(&cnt[ei_dst[e]], 1u);
}

__global__ __launch_bounds__(256) void k_chunksum(const unsigned* __restrict__ cnt,
                                                  unsigned* __restrict__ csum, int N) {
    __shared__ unsigned s[256];
    int i = blockIdx.x * 256 + threadIdx.x;
    s[threadIdx.x] = (i < N) ? cnt[i] : 0u;
    __syncthreads();
    for (int off = 128; off > 0; off >>= 1) {
        if (threadIdx.x < off) s[threadIdx.x] += s[threadIdx.x + off];
        __syncthreads();
    }
    if (threadIdx.x == 0) csum[blockIdx.x] = s[0];
}

__global__ __launch_bounds__(1024) void k_scanchunks(unsigned* __restrict__ csum, int nc) {
    __shared__ unsigned s[1024];
    int t = threadIdx.x;
    unsigned v = (t < nc) ? csum[t] : 0u;
    s[t] = v;
    __syncthreads();
    for (int o = 1; o < 1024; o <<= 1) {
        unsigned x = s[t];
        if (t >= o) x += s[t - o];
        __syncthreads();
        s[t] = x;
        __syncthreads();
    }
    if (t < nc) csum[t] = s[t] - v;   // exclusive
}

__global__ __launch_bounds__(256) void k_scanapply(const unsigned* __restrict__ cnt,
                                                   const unsigned* __restrict__ csum,
                                                   unsigned* __restrict__ off, int N) {
    __shared__ unsigned s[2][256];
    int t = threadIdx.x, i = blockIdx.x * 256 + t;
    unsigned v = (i < N) ? cnt[i] : 0u;
    int cur = 0;
    s[0][t] = v;
    __syncthreads();
    for (int o = 1; o < 256; o <<= 1) {
        unsigned x = s[cur][t];
        if (t >= o) x += s[cur][t - o];
        s[cur ^ 1][t] = x;
        cur ^= 1;
        __syncthreads();
    }
    unsigned excl = s[cur][t] - v + csum[blockIdx.x];
    if (i < N) off[i] = excl;
}

// atomic-free permute: slot = off[d] + rank[e]; payload (src, raw w)
__global__ __launch_bounds__(256) void k_permute(const int* __restrict__ ei,
        const float* __restrict__ w, const unsigned* __restrict__ off,
        const unsigned* __restrict__ rank, float2* __restrict__ sorted, int E) {
    int e = blockIdx.x * 256 + threadIdx.x;
    if (e >= E) return;
    int s = ei[e];
    int d = ei[(size_t)E + e];
    unsigned p = off[d] + rank[e];
    sorted[p] = make_float2(__int_as_float(s), w[e]);
}

// dinv[n] = rsqrt(1 + sum w over CSR segment)
__global__ __launch_bounds__(256) void k_degsum(const unsigned* __restrict__ off,
        const unsigned* __restrict__ cnt, const float2* __restrict__ sorted,
        float* __restrict__ dinv, int N) {
    int l = threadIdx.x & 31;
    int n = blockIdx.x * 8 + (threadIdx.x >> 5);
    if (n >= N) return;
    unsigned base = off[n], len = cnt[n];
    float s = 0.0f;
    for (unsigned i = l; i < len; i += 32) s += sorted[base + i].y;
    #pragma unroll
    for (int o = 16; o >= 1; o >>= 1) s += __shfl_xor(s, o, 32);
    if (l == 0) dinv[n] = rsqrtf(1.0f + s);
}

// xwh[n][c] (bf16) = x[n][:] @ [Wz|Wr|Wh][:, c]
#define GR 16
__global__ __launch_bounds__(256) void k_gemm(const float* __restrict__ x,
        const float* __restrict__ Wz, const float* __restrict__ Wr, const float* __restrict__ Wh,
        unsigned* __restrict__ xwh, int N) {
    __shared__ float Wl[F * GATES];
    __shared__ float xs[GR][F + 1];
    int tid = threadIdx.x;
    for (int i = tid; i < F * GATES; i += 256) {
        int k = i / GATES, c = i % GATES;
        float v;
        if (c < 32)      v = Wz[k * 32 + c];
        else if (c < 64) v = Wr[k * 32 + (c - 32)];
        else             v = Wh[k * 32 + (c - 64)];
        Wl[i] = v;
    }
    int r_local = tid / 16;
    int cb = tid % 16;
    int ntiles = (N + GR - 1) / GR;
    for (int t = blockIdx.x; t < ntiles; t += gridDim.x) {
        int row0 = t * GR;
        __syncthreads();
        for (int i = tid; i < GR * F; i += 256) {
            int r = i / F, k = i % F;
            int g = row0 + r;
            xs[r][k] = (g < N) ? x[(size_t)g * F + k] : 0.0f;
        }
        __syncthreads();
        int grow = row0 + r_local;
        if (grow < N) {
            float acc[6] = {0, 0, 0, 0, 0, 0};
            for (int k = 0; k < F; ++k) {
                float xv = xs[r_local][k];
                const float* wr = &Wl[k * GATES + cb * 6];
                #pragma unroll
                for (int j = 0; j < 6; ++j) acc[j] += xv * wr[j];
            }
            unsigned* o = xwh + (size_t)grow * 48 + cb * 3;
            o[0] = f2b(acc[0]) | (f2b(acc[1]) << 16);
            o[1] = f2b(acc[2]) | (f2b(acc[3]) << 16);
            o[2] = f2b(acc[4]) | (f2b(acc[5]) << 16);
        }
    }
}

// one 32-lane group per dst node, two 16-lane halves (one edge each per step).
// Edge loop: 8-edge blocks; each block issues ALL FOUR dwordx3 gathers back-to-back
// (named regs, no consumer in between) -> ~4 loads in flight per half.
__global__ __launch_bounds__(256, 8) void k_fused(
        const unsigned* __restrict__ off, const unsigned* __restrict__ cnt,
        const float2* __restrict__ sorted,
        const unsigned* __restrict__ xwh, const float* __restrict__ dinv, const float* __restrict__ Hin,
        const float* __restrict__ bz, const float* __restrict__ br, const float* __restrict__ bh,
        const float* __restrict__ Lzw, const float* __restrict__ Lzb,
        const float* __restrict__ Lrw, const float* __restrict__ Lrb,
        const float* __restrict__ Lhw, const float* __restrict__ Lhb,
        const float* __restrict__ linw, const float* __restrict__ linb,
        float* __restrict__ out_probs, float* __restrict__ out_H, int N) {
    int tid = threadIdx.x;
    int l = tid & 31;
    int half = l >> 4;
    int q = l & 15;             // feature sub-block: features 6q..6q+5
    int n = blockIdx.x * 8 + (tid >> 5);
    if (n >= N) return;

    float di = dinv[n];
    float acc0 = 0, acc1 = 0, acc2 = 0, acc3 = 0, acc4 = 0, acc5 = 0;

    unsigned base = off[n], len = cnt[n];
    for (unsigned i0 = 0; i0 < len; i0 += 32) {
        int take = (int)(len - i0); if (take > 32) take = 32;
        nfloat2 ev = {0.0f, 0.0f};
        if (l < take)
            ev = __builtin_nontemporal_load((const nfloat2*)sorted + base + i0 + l);
        int   se = __float_as_int(ev.x);     // 0 for padded lanes
        float me = ev.y * dinv[se];          // 0 for padded lanes

        // 8 edges per block: 4 per half; ALL loads issued before ANY unpack/FMA.
        #define BLK(bb) {                                                          \
            int   s0 = __shfl(se, (bb) + half,      32);                           \
            int   s1 = __shfl(se, (bb) + 2 + half,  32);                           \
            int   s2 = __shfl(se, (bb) + 4 + half,  32);                           \
            int   s3 = __shfl(se, (bb) + 6 + half,  32);                           \
            float w0 = __shfl(me, (bb) + half,      32);                           \
            float w1 = __shfl(me, (bb) + 2 + half,  32);                           \
            float w2 = __shfl(me, (bb) + 4 + half,  32);                           \
            float w3 = __shfl(me, (bb) + 6 + half,  32);                           \
            const unsigned* p0 = xwh + (size_t)s0 * 48 + q * 3;                    \
            const unsigned* p1 = xwh + (size_t)s1 * 48 + q * 3;                    \
            const unsigned* p2 = xwh + (size_t)s2 * 48 + q * 3;                    \
            const unsigned* p3 = xwh + (size_t)s3 * 48 + q * 3;                    \
            unsigned a0 = p0[0], a1 = p0[1], a2 = p0[2];                           \
            unsigned b0 = p1[0], b1 = p1[1], b2 = p1[2];                           \
            unsigned c0 = p2[0], c1 = p2[1], c2 = p2[2];                           \
            unsigned d0 = p3[0], d1 = p3[1], d2 = p3[2];                           \
            acc0 += w0 * __uint_as_float(a0 << 16);                                \
            acc1 += w0 * __uint_as_float(a0 & 0xFFFF0000u);                        \
            acc2 += w0 * __uint_as_float(a1 << 16);                                \
            acc3 += w0 * __uint_as_float(a1 & 0xFFFF0000u);                        \
            acc4 += w0 * __uint_as_float(a2 << 16);                                \
            acc5 += w0 * __uint_as_float(a2 & 0xFFFF0000u);                        \
            acc0 += w1 * __uint_as_float(b0 << 16);                                \
            acc1 += w1 * __uint_as_float(b0 & 0xFFFF0000u);                        \
            acc2 += w1 * __uint_as_float(b1 << 16);                                \
            acc3 += w1 * __uint_as_float(b1 & 0xFFFF0000u);                        \
            acc4 += w1 * __uint_as_float(b2 << 16);                                \
            acc5 += w1 * __uint_as_float(b2 & 0xFFFF0000u);                        \
            acc0 += w2 * __uint_as_float(c0 << 16);                                \
            acc1 += w2 * __uint_as_float(c0 & 0xFFFF0000u);                        \
            acc2 += w2 * __uint_as_float(c1 << 16);                                \
            acc3 += w2 * __uint_as_float(c1 & 0xFFFF0000u);                        \
            acc4 += w2 * __uint_as_float(c2 << 16);                                \
            acc5 += w2 * __uint_as_float(c2 & 0xFFFF0000u);                        \
            acc0 += w3 * __uint_as_float(d0 << 16);                                \
            acc1 += w3 * __uint_as_float(d0 & 0xFFFF0000u);                        \
            acc2 += w3 * __uint_as_float(d1 << 16);                                \
            acc3 += w3 * __uint_as_float(d1 & 0xFFFF0000u);                        \
            acc4 += w3 * __uint_as_float(d2 << 16);                                \
            acc5 += w3 * __uint_as_float(d2 & 0xFFFF0000u); }

        BLK(0)
        if (take > 8)  BLK(8)
        if (take > 16) BLK(16)
        if (take > 24) BLK(24)
        #undef BLK
    }
    // fold the two halves
    acc0 += __shfl_xor(acc0, 16, 32);
    acc1 += __shfl_xor(acc1, 16, 32);
    acc2 += __shfl_xor(acc2, 16, 32);
    acc3 += __shfl_xor(acc3, 16, 32);
    acc4 += __shfl_xor(acc4, 16, 32);
    acc5 += __shfl_xor(acc5, 16, 32);
    // self-loop + di scale + bias: g_i = di*(acc_i + di*x_i) + b[f], f = q*6+i
    float g0, g1, g2, g3, g4, g5;
    {
        const unsigned* p = xwh + (size_t)n * 48 + q * 3;
        unsigned u0 = p[0], u1 = p[1], u2 = p[2];
        #define BIAS(f) ((f) < 32 ? bz[(f)] : ((f) < 64 ? br[(f) - 32] : bh[(f) - 64]))
        int f = q * 6;
        g0 = di * (acc0 + di * __uint_as_float(u0 << 16))         + BIAS(f);
        g1 = di * (acc1 + di * __uint_as_float(u0 & 0xFFFF0000u)) + BIAS(f + 1);
        g2 = di * (acc2 + di * __uint_as_float(u1 << 16))         + BIAS(f + 2);
        g3 = di * (acc3 + di * __uint_as_float(u1 & 0xFFFF0000u)) + BIAS(f + 3);
        g4 = di * (acc4 + di * __uint_as_float(u2 << 16))         + BIAS(f + 4);
        g5 = di * (acc5 + di * __uint_as_float(u2 & 0xFFFF0000u)) + BIAS(f + 5);
        #undef BIAS
    }
    // transpose to per-lane-feature layout: lane l wants feature f at (mm=f/6, ii=f%6)
    #define GATHERF(out, fexp) { int ff = (fexp); int mm = ff / 6, ii = ff % 6;            \
        float t0 = __shfl(g0, mm, 32), t1 = __shfl(g1, mm, 32), t2 = __shfl(g2, mm, 32),   \
              t3 = __shfl(g3, mm, 32), t4 = __shfl(g4, mm, 32), t5 = __shfl(g5, mm, 32);   \
        out = ii == 0 ? t0 : ii == 1 ? t1 : ii == 2 ? t2 : ii == 3 ? t3 : ii == 4 ? t4 : t5; }
    float gz, gr, gh;
    GATHERF(gz, l);
    GATHERF(gr, 32 + l);
    GATHERF(gh, 64 + l);
    #undef GATHERF

    float Hd = Hin[(size_t)n * HID + l];

    float az = Lzb[l], ar = Lrb[l];
    #pragma unroll 4
    for (int k = 0; k < 32; ++k) {
        float gzk = __shfl(gz, k, 32);
        float grk = __shfl(gr, k, 32);
        float Hk  = __shfl(Hd, k, 32);
        az += gzk * Lzw[k * 32 + l] + Hk * Lzw[(32 + k) * 32 + l];
        ar += grk * Lrw[k * 32 + l] + Hk * Lrw[(32 + k) * 32 + l];
    }
    float Z  = 1.0f / (1.0f + __expf(-az));
    float Rg = 1.0f / (1.0f + __expf(-ar));
    float HR = Hd * Rg;
    float ah = Lhb[l];
    #pragma unroll 4
    for (int k = 0; k < 32; ++k) {
        float ghk = __shfl(gh, k, 32);
        float HRk = __shfl(HR, k, 32);
        ah += ghk * Lhw[k * 32 + l] + HRk * Lhw[(32 + k) * 32 + l];
    }
    float Ht = tanhf(ah);
    float Hn = Z * Hd + (1.0f - Z) * Ht;
    float h = fmaxf(Hn, 0.0f);

    float logit = (l < 10) ? linb[l] : -INFINITY;
    #pragma unroll 4
    for (int k = 0; k < 32; ++k) {
        float hk = __shfl(h, k, 32);
        if (l < 10) logit += hk * linw[k * 10 + l];
    }
    float mx = logit;
    #pragma unroll
    for (int o = 8; o >= 1; o >>= 1) mx = fmaxf(mx, __shfl_xor(mx, o, 16));
    float ex = (l < 10) ? __expf(logit - mx) : 0.0f;
    float sum = ex;
    #pragma unroll
    for (int o = 8; o >= 1; o >>= 1) sum += __shfl_xor(sum, o, 16);
    if (l < 10) out_probs[(size_t)n * 10 + l] = ex / sum;
    out_H[(size_t)n * HID + l] = Hd;
}

extern "C" void kernel_launch(void* const* d_in, const int* in_sizes, int n_in,
                              void* d_out, int out_size, void* d_ws, size_t ws_size,
                              hipStream_t stream) {
    const float* x    = (const float*)d_in[0];
    const int*   ei   = (const int*)d_in[1];     // int32, layout [2][E]
    const float* ew   = (const float*)d_in[2];
    const float* H    = (const float*)d_in[3];
    const float* Wz   = (const float*)d_in[4];
    const float* bz   = (const float*)d_in[5];
    const float* Wr   = (const float*)d_in[6];
    const float* br   = (const float*)d_in[7];
    const float* Wh   = (const float*)d_in[8];
    const float* bh   = (const float*)d_in[9];
    const float* Lzw  = (const float*)d_in[10];
    const float* Lzb  = (const float*)d_in[11];
    const float* Lrw  = (const float*)d_in[12];
    const float* Lrb  = (const float*)d_in[13];
    const float* Lhw  = (const float*)d_in[14];
    const float* Lhb  = (const float*)d_in[15];
    const float* linw = (const float*)d_in[16];
    const float* linb = (const float*)d_in[17];

    int N = in_sizes[0] / F;
    int E = in_sizes[2];
    int nchunk = (N + CHUNK - 1) / CHUNK;   // 391 for N=100k (scan supports <=1024)

    float* ws = (float*)d_ws;
    unsigned* xwh    = (unsigned*)ws;                       // N*48 u32 (N*96 bf16)
    float2*   sorted = (float2*)(ws + (size_t)N * 48);
    float*    dinv   = ws + (size_t)N * 48 + (size_t)E * 2;
    unsigned* cnt    = (unsigned*)(dinv + N);
    unsigned* off    = cnt + N;
    unsigned* csum   = off + N;
    unsigned* rank   = xwh;    // overlay: E u32 (12.8MB) <= N*48 u32 (19.2MB); dead before k_gemm

    float* out_probs = (float*)d_out;
    float* out_H     = (float*)d_out + (size_t)N * 10;

    hipMemsetAsync(cnt, 0, (size_t)N * sizeof(unsigned), stream);
    k_hist<<<(E + 255) / 256, 256, 0, stream>>>(ei + (size_t)E, cnt, rank, E);
    k_chunksum<<<nchunk, 256, 0, stream>>>(cnt, csum, N);
    k_scanchunks<<<1, 1024, 0, stream>>>(csum, nchunk);
    k_scanapply<<<nchunk, 256, 0, stream>>>(cnt, csum, off, N);
    k_permute<<<(E + 255) / 256, 256, 0, stream>>>(ei, ew, off, rank, sorted, E);
    k_degsum<<<(N + 7) / 8, 256, 0, stream>>>(off, cnt, sorted, dinv, N);
    k_gemm<<<2048, 256, 0, stream>>>(x, Wz, Wr, Wh, xwh, N);
    k_fused<<<(N + 7) / 8, 256, 0, stream>>>(off, cnt, sorted, xwh, dinv, H,
                                             bz, br, bh, Lzw, Lzb, Lrw, Lrb, Lhw, Lhb,
                                             linw, linb, out_probs, out_H, N);
}